// Round 1
// 1044.846 us; speedup vs baseline: 1.0234x; 1.0234x over previous
//
#include <hip/hip_runtime.h>
#include <math.h>

#define B_  2
#define S_  2048
#define E_  768
#define H_  12
#define TB_ 128
#define D_  64

typedef __attribute__((ext_vector_type(4))) float f32x4;
typedef __attribute__((ext_vector_type(8))) short bf16x8;

// ---------------------------------------------------------------------------
// Split-bf16 helpers: x = hi + lo with RNE rounding at each level.
// ---------------------------------------------------------------------------
__device__ inline unsigned short bf16_rne(float x) {
    unsigned u = __float_as_uint(x);
    unsigned r = u + 0x7FFFu + ((u >> 16) & 1u);
    return (unsigned short)(r >> 16);
}
__device__ inline void split1(float x, unsigned short& h, unsigned short& l) {
    h = bf16_rne(x);
    float hf = __uint_as_float((unsigned)h << 16);
    l = bf16_rne(x - hf);
}

// LDS tile [128 rows][64 bf16], XOR-swizzled in 16B chunks (stride 64, no pad).
// Fragment reads (16 lanes, same chunk idx, rows +0..15) land 2-way max (free).
__device__ inline int lds_off(int row, int sh) {   // sh = short offset 0..63
    int ch = sh >> 3;                              // 16B chunk 0..7
    int in = sh & 7;
    return row * 64 + (((ch ^ (row & 7)) << 3) | in);
}

// ---------------------------------------------------------------------------
// Linear GEMM via split-bf16 MFMA: C[M,N] = A[M,K] @ W[N,K]^T + bias[N].
// 128x128 tile per block, 4 waves; wave w owns rows [w*32, w*32+32) x all
// 128 cols as a 2x8 grid of 16x16x32 MFMA tiles. K looped in 64-wide chunks.
// C = Ahi.Whi^T + Ahi.Wlo^T + Alo.Whi^T  (lo.lo skipped, ~2^-16 rel/term).
// ---------------------------------------------------------------------------
__global__ __launch_bounds__(256)
void gemm_bias_mfma(const float* __restrict__ A, const float* __restrict__ W,
                    const float* __restrict__ bias, float* __restrict__ C,
                    int M, int N, int K) {
    __shared__ unsigned short Ahi[128 * 64];
    __shared__ unsigned short Alo[128 * 64];
    __shared__ unsigned short Whi[128 * 64];
    __shared__ unsigned short Wlo[128 * 64];

    const int m0 = blockIdx.y * 128;
    const int n0 = blockIdx.x * 128;
    const int tid  = threadIdx.x;
    const int wv   = tid >> 6;         // wave 0..3
    const int lane = tid & 63;
    const int l15  = lane & 15;
    const int quad = lane >> 4;        // 0..3

    f32x4 acc[2][8] = {};

    for (int k0 = 0; k0 < K; k0 += 64) {
        // ---- stage: load fp32, split to hi/lo bf16, write swizzled LDS ----
        {
            const int row = tid >> 4;      // 0..15 within pass
            const int c4  = tid & 15;      // float4 index (64 floats/row)
            #pragma unroll
            for (int ps = 0; ps < 8; ++ps) {
                int r = ps * 16 + row;
                float4 av = *(const float4*)&A[(size_t)(m0 + r) * K + k0 + c4 * 4];
                float4 wv4 = *(const float4*)&W[(size_t)(n0 + r) * K + k0 + c4 * 4];
                ushort4 ah, al, wh, wl;
                split1(av.x, ah.x, al.x); split1(av.y, ah.y, al.y);
                split1(av.z, ah.z, al.z); split1(av.w, ah.w, al.w);
                split1(wv4.x, wh.x, wl.x); split1(wv4.y, wh.y, wl.y);
                split1(wv4.z, wh.z, wl.z); split1(wv4.w, wh.w, wl.w);
                int o = lds_off(r, c4 * 4);
                *(ushort4*)&Ahi[o] = ah;  *(ushort4*)&Alo[o] = al;
                *(ushort4*)&Whi[o] = wh;  *(ushort4*)&Wlo[o] = wl;
            }
        }
        __syncthreads();

        // ---- MFMA over this 64-wide K chunk ----
        #pragma unroll
        for (int kk = 0; kk < 64; kk += 32) {
            bf16x8 aHi[2], aLo[2];
            #pragma unroll
            for (int ti = 0; ti < 2; ++ti) {
                int ar = wv * 32 + ti * 16 + l15;
                int sh = kk + quad * 8;
                aHi[ti] = *(const bf16x8*)&Ahi[lds_off(ar, sh)];
                aLo[ti] = *(const bf16x8*)&Alo[lds_off(ar, sh)];
            }
            #pragma unroll
            for (int tj = 0; tj < 8; ++tj) {
                int br = tj * 16 + l15;
                int sh = kk + quad * 8;
                bf16x8 bHi = *(const bf16x8*)&Whi[lds_off(br, sh)];
                bf16x8 bLo = *(const bf16x8*)&Wlo[lds_off(br, sh)];
                #pragma unroll
                for (int ti = 0; ti < 2; ++ti) {
                    acc[ti][tj] = __builtin_amdgcn_mfma_f32_16x16x32_bf16(aHi[ti], bHi, acc[ti][tj], 0, 0, 0);
                    acc[ti][tj] = __builtin_amdgcn_mfma_f32_16x16x32_bf16(aHi[ti], bLo, acc[ti][tj], 0, 0, 0);
                    acc[ti][tj] = __builtin_amdgcn_mfma_f32_16x16x32_bf16(aLo[ti], bHi, acc[ti][tj], 0, 0, 0);
                }
            }
        }
        __syncthreads();
    }

    // ---- epilogue: bias add, store ----
    #pragma unroll
    for (int ti = 0; ti < 2; ++ti) {
        const int ib = m0 + wv * 32 + ti * 16 + quad * 4;
        #pragma unroll
        for (int tj = 0; tj < 8; ++tj) {
            int col = n0 + tj * 16 + l15;
            float bv = bias[col];
            f32x4 a = acc[ti][tj];
            #pragma unroll
            for (int r = 0; r < 4; ++r)
                C[(size_t)(ib + r) * N + col] = a[r] + bv;
        }
    }
}

// ---------------------------------------------------------------------------
__global__ void tb_kernel(const float* __restrict__ task_bias,
                          const float* __restrict__ Wtb,
                          const float* __restrict__ btb,
                          float* __restrict__ tb) {
    int t = threadIdx.x;
    if (t < B_ * H_) {
        int b = t / H_, h = t % H_;
        float s = 0.f;
        for (int i = 0; i < TB_; ++i)
            s += task_bias[b * TB_ + i] * Wtb[h * TB_ + i];
        tb[t] = s + btb[h];
    }
}

// ---------------------------------------------------------------------------
// Scores via split-bf16 MFMA:
//   p[b,h,i,j] = mask[b,j] ? exp(q.k/8 + tb[b,h]) : 0   (unnormalized)
// 128x128 tile per block (grid 16,16,24), 4 waves; wave w owns rows
// [w*32, w*32+32) x all 128 cols as a 2x8 grid of 16x16x32 MFMA tiles.
// S = qhi.khi^T + qhi.klo^T + qlo.khi^T  (lo.lo skipped, ~2^-17 rel).
// ---------------------------------------------------------------------------
__global__ __launch_bounds__(256)
void scores_kernel(const float* __restrict__ q, const float* __restrict__ k,
                   const int* __restrict__ mask, const float* __restrict__ tb,
                   float* __restrict__ attn, float* __restrict__ rowsum) {
    __shared__ unsigned short Qhi[128 * 64];
    __shared__ unsigned short Qlo[128 * 64];
    __shared__ unsigned short Khi[128 * 64];
    __shared__ unsigned short Klo[128 * 64];

    const int bh = blockIdx.z;
    const int b = bh / H_, h = bh % H_;
    const int i0 = blockIdx.y * 128;   // query rows
    const int j0 = blockIdx.x * 128;   // key cols
    const int tid  = threadIdx.x;
    const int wv   = tid >> 6;         // wave 0..3
    const int lane = tid & 63;
    const int l15  = lane & 15;
    const int quad = lane >> 4;        // 0..3

    const float* qbase = q + (size_t)b * S_ * E_ + h * D_;
    const float* kbase = k + (size_t)b * S_ * E_ + h * D_;

    // ---- stage: load fp32, split to hi/lo bf16, write LDS ----
    {
        const int row = tid >> 4;      // 0..15 within pass
        const int c4  = tid & 15;      // float4 index 0..15 (64 floats/row)
        #pragma unroll
        for (int ps = 0; ps < 8; ++ps) {
            int r = ps * 16 + row;
            float4 qv = *(const float4*)&qbase[(size_t)(i0 + r) * E_ + c4 * 4];
            float4 kv = *(const float4*)&kbase[(size_t)(j0 + r) * E_ + c4 * 4];
            ushort4 qh, ql, kh, kl;
            split1(qv.x, qh.x, ql.x); split1(qv.y, qh.y, ql.y);
            split1(qv.z, qh.z, ql.z); split1(qv.w, qh.w, ql.w);
            split1(kv.x, kh.x, kl.x); split1(kv.y, kh.y, kl.y);
            split1(kv.z, kh.z, kl.z); split1(kv.w, kh.w, kl.w);
            int o = lds_off(r, c4 * 4);
            *(ushort4*)&Qhi[o] = qh;  *(ushort4*)&Qlo[o] = ql;
            *(ushort4*)&Khi[o] = kh;  *(ushort4*)&Klo[o] = kl;
        }
    }
    __syncthreads();

    // ---- MFMA compute ----
    f32x4 acc[2][8] = {};
    #pragma unroll
    for (int kk = 0; kk < 64; kk += 32) {
        bf16x8 aHi[2], aLo[2];
        #pragma unroll
        for (int ti = 0; ti < 2; ++ti) {
            int ar = wv * 32 + ti * 16 + l15;
            int sh = kk + quad * 8;
            aHi[ti] = *(const bf16x8*)&Qhi[lds_off(ar, sh)];
            aLo[ti] = *(const bf16x8*)&Qlo[lds_off(ar, sh)];
        }
        #pragma unroll
        for (int tj = 0; tj < 8; ++tj) {
            int br = tj * 16 + l15;
            int sh = kk + quad * 8;
            bf16x8 bHi = *(const bf16x8*)&Khi[lds_off(br, sh)];
            bf16x8 bLo = *(const bf16x8*)&Klo[lds_off(br, sh)];
            #pragma unroll
            for (int ti = 0; ti < 2; ++ti) {
                acc[ti][tj] = __builtin_amdgcn_mfma_f32_16x16x32_bf16(aHi[ti], bHi, acc[ti][tj], 0, 0, 0);
                acc[ti][tj] = __builtin_amdgcn_mfma_f32_16x16x32_bf16(aHi[ti], bLo, acc[ti][tj], 0, 0, 0);
                acc[ti][tj] = __builtin_amdgcn_mfma_f32_16x16x32_bf16(aLo[ti], bHi, acc[ti][tj], 0, 0, 0);
            }
        }
    }

    // ---- epilogue: exp, store, rowsum ----
    const float tbv = tb[bh];
    const int* mrow = mask + b * S_ + j0;
    int m_[8];
    #pragma unroll
    for (int tj = 0; tj < 8; ++tj) m_[tj] = mrow[tj * 16 + l15];

    float* attnbase = attn + (size_t)bh * S_ * S_;
    #pragma unroll
    for (int ti = 0; ti < 2; ++ti) {
        float rs[4] = {0.f, 0.f, 0.f, 0.f};
        const int ib = i0 + wv * 32 + ti * 16 + quad * 4;  // +r = global row
        #pragma unroll
        for (int tj = 0; tj < 8; ++tj) {
            f32x4 a = acc[ti][tj];
            #pragma unroll
            for (int r = 0; r < 4; ++r) {
                float sc = a[r] * 0.125f + tbv;
                float p = m_[tj] ? __expf(sc) : 0.f;
                attnbase[(size_t)(ib + r) * S_ + j0 + tj * 16 + l15] = p;
                rs[r] += p;
            }
        }
        #pragma unroll
        for (int off = 1; off < 16; off <<= 1) {
            #pragma unroll
            for (int r = 0; r < 4; ++r)
                rs[r] += __shfl_xor(rs[r], off, 64);
        }
        if (l15 == 0) {
            #pragma unroll
            for (int r = 0; r < 4; ++r)
                atomicAdd(&rowsum[(size_t)bh * S_ + ib + r], rs[r]);
        }
    }
}

// ---------------------------------------------------------------------------
// ctx = softmax(p) @ v fused with normalization write-back (unchanged).
// ---------------------------------------------------------------------------
__global__ __launch_bounds__(256)
void ctx_kernel(float* __restrict__ attn, const float* __restrict__ rowsum,
                const float* __restrict__ v, float* __restrict__ ctx) {
    __shared__ float Ps[64][68];
    __shared__ float Vs[64][68];
    __shared__ float invs[64];
    const int bh = blockIdx.y;
    const int b = bh / H_, h = bh % H_;
    const int i0 = blockIdx.x * 64;
    const int tid = threadIdx.x;
    const int tx = tid & 15, ty = tid >> 4;

    if (tid < 64)
        invs[tid] = 1.0f / rowsum[(size_t)bh * S_ + i0 + tid];
    __syncthreads();

    const float* vbase = v + (size_t)b * S_ * E_ + h * D_;
    float acc[4][4] = {};

    for (int kc = 0; kc < S_; kc += 64) {
        #pragma unroll
        for (int it = 0; it < 4; ++it) {
            int i   = tid + it * 256;
            int row = i >> 4;
            int qd  = i & 15;
            size_t paddr = ((size_t)bh * S_ + i0 + row) * S_ + kc + qd * 4;
            float4 p = *(const float4*)&attn[paddr];
            float iv = invs[row];
            p.x *= iv; p.y *= iv; p.z *= iv; p.w *= iv;
            *(float4*)&attn[paddr] = p;
            Ps[qd*4+0][row] = p.x; Ps[qd*4+1][row] = p.y;
            Ps[qd*4+2][row] = p.z; Ps[qd*4+3][row] = p.w;
            float4 vv = *(const float4*)&vbase[(size_t)(kc + row) * E_ + qd * 4];
            *(float4*)&Vs[row][qd * 4] = vv;
        }
        __syncthreads();
        #pragma unroll
        for (int kk = 0; kk < 64; ++kk) {
            float4 av = *(const float4*)&Ps[kk][ty * 4];
            float4 wv = *(const float4*)&Vs[kk][tx * 4];
            float a_[4] = {av.x, av.y, av.z, av.w};
            float w_[4] = {wv.x, wv.y, wv.z, wv.w};
            #pragma unroll
            for (int i = 0; i < 4; ++i)
                #pragma unroll
                for (int j = 0; j < 4; ++j)
                    acc[i][j] += a_[i] * w_[j];
        }
        __syncthreads();
    }

    #pragma unroll
    for (int i = 0; i < 4; ++i) {
        float4 o = {acc[i][0], acc[i][1], acc[i][2], acc[i][3]};
        *(float4*)&ctx[(size_t)(b * S_ + i0 + ty * 4 + i) * E_ + h * D_ + tx * 4] = o;
    }
}

// ---------------------------------------------------------------------------
extern "C" void kernel_launch(void* const* d_in, const int* in_sizes, int n_in,
                              void* d_out, int out_size, void* d_ws, size_t ws_size,
                              hipStream_t stream) {
    const float* query     = (const float*)d_in[0];
    const float* key       = (const float*)d_in[1];
    const float* value     = (const float*)d_in[2];
    const float* task_bias = (const float*)d_in[3];
    const int*   mask      = (const int*)  d_in[4];
    const float* Wq  = (const float*)d_in[5];
    const float* bq  = (const float*)d_in[6];
    const float* Wk  = (const float*)d_in[7];
    const float* bk  = (const float*)d_in[8];
    const float* Wv  = (const float*)d_in[9];
    const float* bv  = (const float*)d_in[10];
    const float* Wtb = (const float*)d_in[11];
    const float* btb = (const float*)d_in[12];
    const float* Wo  = (const float*)d_in[13];
    const float* bo  = (const float*)d_in[14];

    const size_t BSE = (size_t)B_ * S_ * E_;
    float* out  = (float*)d_out;
    float* attn = (float*)d_out + BSE;

    float* ws     = (float*)d_ws;
    float* qws    = ws;
    float* kws    = qws + BSE;
    float* vws    = kws + BSE;
    float* ctxws  = vws + BSE;
    float* rowsum = ctxws + BSE;
    float* tbws   = rowsum + (size_t)B_ * H_ * S_;

    hipMemsetAsync(rowsum, 0, (size_t)B_ * H_ * S_ * sizeof(float), stream);

    const dim3 blk(256);
    const dim3 gProj(E_ / 128, (B_ * S_) / 128);      // (6, 32)

    gemm_bias_mfma<<<gProj, blk, 0, stream>>>(query, Wq, bq, qws, B_ * S_, E_, E_);
    gemm_bias_mfma<<<gProj, blk, 0, stream>>>(key,   Wk, bk, kws, B_ * S_, E_, E_);
    gemm_bias_mfma<<<gProj, blk, 0, stream>>>(value, Wv, bv, vws, B_ * S_, E_, E_);
    tb_kernel<<<1, 64, 0, stream>>>(task_bias, Wtb, btb, tbws);

    const dim3 gSc(S_ / 128, S_ / 128, B_ * H_);      // (16, 16, 24)
    scores_kernel<<<gSc, blk, 0, stream>>>(qws, kws, mask, tbws, attn, rowsum);

    const dim3 gCtx(S_ / 64, B_ * H_);                // (32, 24)
    ctx_kernel<<<gCtx, blk, 0, stream>>>(attn, rowsum, vws, ctxws);

    gemm_bias_mfma<<<gProj, blk, 0, stream>>>(ctxws, Wo, bo, out, B_ * S_, E_, E_);
}

// Round 3
// 923.084 us; speedup vs baseline: 1.1584x; 1.1319x over previous
//
#include <hip/hip_runtime.h>
#include <math.h>

#define B_  2
#define S_  2048
#define E_  768
#define H_  12
#define TB_ 128
#define D_  64

typedef __attribute__((ext_vector_type(4))) float f32x4;
typedef __attribute__((ext_vector_type(8))) short bf16x8;

// ---------------------------------------------------------------------------
// Split-bf16 helpers: x = hi + lo with RNE rounding at each level.
// ---------------------------------------------------------------------------
__device__ inline unsigned short bf16_rne(float x) {
    unsigned u = __float_as_uint(x);
    unsigned r = u + 0x7FFFu + ((u >> 16) & 1u);
    return (unsigned short)(r >> 16);
}
__device__ inline void split1(float x, unsigned short& h, unsigned short& l) {
    h = bf16_rne(x);
    float hf = __uint_as_float((unsigned)h << 16);
    l = bf16_rne(x - hf);
}

// LDS tile [rows][64 bf16], XOR-swizzled in 16B chunks (stride 64, no pad).
__device__ inline int lds_off(int row, int sh) {   // sh = short offset 0..63
    int ch = sh >> 3;                              // 16B chunk 0..7
    int in = sh & 7;
    return row * 64 + (((ch ^ (row & 7)) << 3) | in);
}

// ---------------------------------------------------------------------------
// One-time fp32 -> (hi, lo) bf16 split. Pure BW. n4 = n/4.
// ---------------------------------------------------------------------------
__global__ __launch_bounds__(256)
void split_kernel(const float* __restrict__ in, unsigned short* __restrict__ hi,
                  unsigned short* __restrict__ lo, int n4) {
    int i = blockIdx.x * blockDim.x + threadIdx.x;
    int stride = gridDim.x * blockDim.x;
    for (; i < n4; i += stride) {
        float4 v = *(const float4*)&in[(size_t)i * 4];
        ushort4 h, l;
        split1(v.x, h.x, l.x); split1(v.y, h.y, l.y);
        split1(v.z, h.z, l.z); split1(v.w, h.w, l.w);
        *(ushort4*)&hi[(size_t)i * 4] = h;
        *(ushort4*)&lo[(size_t)i * 4] = l;
    }
}

// ---------------------------------------------------------------------------
// Linear GEMM via split-bf16 MFMA, pre-split A operand.
// C[M,N] = A[M,K] @ W[N,K]^T + bias[N], 3-term (hi.hi + hi.lo + lo.hi).
// 128x128 tile, 4 waves; wave w owns rows [w*32,w*32+32) x 128 cols.
// WPRE=1: W pre-split bf16.  WPRE=0: W fp32, split in-kernel.
// EPI: 0 = fp32 C, 1 = split bf16 (Chi/Clo), 2 = V^T split scatter [bh][d][S].
// ---------------------------------------------------------------------------
template<int WPRE, int EPI>
__global__ __launch_bounds__(256)
void gemm_mfma(const unsigned short* __restrict__ Ahi_g,
               const unsigned short* __restrict__ Alo_g,
               const unsigned short* __restrict__ Whi_g,
               const unsigned short* __restrict__ Wlo_g,
               const float* __restrict__ Wf_g,
               const float* __restrict__ bias,
               float* __restrict__ Cf,
               unsigned short* __restrict__ Chi, unsigned short* __restrict__ Clo,
               int M, int N, int K) {
    __shared__ unsigned short Ahi[128 * 64];
    __shared__ unsigned short Alo[128 * 64];
    __shared__ unsigned short Whi[128 * 64];
    __shared__ unsigned short Wlo[128 * 64];

    const int m0 = blockIdx.y * 128;
    const int n0 = blockIdx.x * 128;
    const int tid  = threadIdx.x;
    const int wv   = tid >> 6;
    const int lane = tid & 63;
    const int l15  = lane & 15;
    const int quad = lane >> 4;

    f32x4 acc[2][8] = {};

    for (int k0 = 0; k0 < K; k0 += 64) {
        // ---- stage A (and W if pre-split): pure bf16x8 copies ----
        #pragma unroll
        for (int it = 0; it < 4; ++it) {
            int idx = it * 256 + tid;
            int r = idx >> 3, c8 = idx & 7;
            int o = r * 64 + (((c8 ^ (r & 7)) << 3));
            size_t ga = (size_t)(m0 + r) * K + k0 + c8 * 8;
            *(bf16x8*)&Ahi[o] = *(const bf16x8*)&Ahi_g[ga];
            *(bf16x8*)&Alo[o] = *(const bf16x8*)&Alo_g[ga];
            if constexpr (WPRE) {
                size_t gw = (size_t)(n0 + r) * K + k0 + c8 * 8;
                *(bf16x8*)&Whi[o] = *(const bf16x8*)&Whi_g[gw];
                *(bf16x8*)&Wlo[o] = *(const bf16x8*)&Wlo_g[gw];
            }
        }
        if constexpr (!WPRE) {
            const int row = tid >> 4, c4 = tid & 15;
            #pragma unroll
            for (int ps = 0; ps < 8; ++ps) {
                int r = ps * 16 + row;
                float4 w = *(const float4*)&Wf_g[(size_t)(n0 + r) * K + k0 + c4 * 4];
                ushort4 wh, wl;
                split1(w.x, wh.x, wl.x); split1(w.y, wh.y, wl.y);
                split1(w.z, wh.z, wl.z); split1(w.w, wh.w, wl.w);
                int o = lds_off(r, c4 * 4);
                *(ushort4*)&Whi[o] = wh;  *(ushort4*)&Wlo[o] = wl;
            }
        }
        __syncthreads();

        // ---- MFMA over this 64-wide K chunk ----
        #pragma unroll
        for (int kk = 0; kk < 64; kk += 32) {
            bf16x8 aHi[2], aLo[2];
            #pragma unroll
            for (int ti = 0; ti < 2; ++ti) {
                int ar = wv * 32 + ti * 16 + l15;
                int sh = kk + quad * 8;
                aHi[ti] = *(const bf16x8*)&Ahi[lds_off(ar, sh)];
                aLo[ti] = *(const bf16x8*)&Alo[lds_off(ar, sh)];
            }
            #pragma unroll
            for (int tj = 0; tj < 8; ++tj) {
                int br = tj * 16 + l15;
                int sh = kk + quad * 8;
                bf16x8 bHi = *(const bf16x8*)&Whi[lds_off(br, sh)];
                bf16x8 bLo = *(const bf16x8*)&Wlo[lds_off(br, sh)];
                #pragma unroll
                for (int ti = 0; ti < 2; ++ti) {
                    acc[ti][tj] = __builtin_amdgcn_mfma_f32_16x16x32_bf16(aHi[ti], bHi, acc[ti][tj], 0, 0, 0);
                    acc[ti][tj] = __builtin_amdgcn_mfma_f32_16x16x32_bf16(aHi[ti], bLo, acc[ti][tj], 0, 0, 0);
                    acc[ti][tj] = __builtin_amdgcn_mfma_f32_16x16x32_bf16(aLo[ti], bHi, acc[ti][tj], 0, 0, 0);
                }
            }
        }
        __syncthreads();
    }

    // ---- epilogue ----
    #pragma unroll
    for (int ti = 0; ti < 2; ++ti) {
        const int ib = m0 + wv * 32 + ti * 16 + quad * 4;
        #pragma unroll
        for (int tj = 0; tj < 8; ++tj) {
            int col = n0 + tj * 16 + l15;
            float bv = bias[col];
            f32x4 a = acc[ti][tj];
            #pragma unroll
            for (int r = 0; r < 4; ++r) {
                float val = a[r] + bv;
                if constexpr (EPI == 0) {
                    Cf[(size_t)(ib + r) * N + col] = val;
                } else if constexpr (EPI == 1) {
                    unsigned short hh, ll;
                    split1(val, hh, ll);
                    Chi[(size_t)(ib + r) * N + col] = hh;
                    Clo[(size_t)(ib + r) * N + col] = ll;
                } else {
                    // V^T scatter: token = ib+r, col = h*64+d  ->  [bt*H+h][d][s]
                    int token = ib + r;
                    int bt = token >> 11, s = token & (S_ - 1);
                    int hh_ = col >> 6, d = col & 63;
                    size_t oa = ((size_t)(bt * H_ + hh_) * 64 + d) * S_ + s;
                    unsigned short hh, ll;
                    split1(val, hh, ll);
                    Chi[oa] = hh;
                    Clo[oa] = ll;
                }
            }
        }
    }
}

// ---------------------------------------------------------------------------
__global__ void tb_kernel(const float* __restrict__ task_bias,
                          const float* __restrict__ Wtb,
                          const float* __restrict__ btb,
                          float* __restrict__ tb) {
    int t = threadIdx.x;
    if (t < B_ * H_) {
        int b = t / H_, h = t % H_;
        float s = 0.f;
        for (int i = 0; i < TB_; ++i)
            s += task_bias[b * TB_ + i] * Wtb[h * TB_ + i];
        tb[t] = s + btb[h];
    }
}

// ---------------------------------------------------------------------------
// Scores via split-bf16 MFMA, inputs pre-split (no in-kernel split).
//   p[b,h,i,j] = mask[b,j] ? exp(q.k/8 + tb[b,h]) : 0   (unnormalized)
// ---------------------------------------------------------------------------
__global__ __launch_bounds__(256)
void scores_kernel(const unsigned short* __restrict__ qhi_g,
                   const unsigned short* __restrict__ qlo_g,
                   const unsigned short* __restrict__ khi_g,
                   const unsigned short* __restrict__ klo_g,
                   const int* __restrict__ mask, const float* __restrict__ tb,
                   float* __restrict__ attn, float* __restrict__ rowsum) {
    __shared__ unsigned short Qhi[128 * 64];
    __shared__ unsigned short Qlo[128 * 64];
    __shared__ unsigned short Khi[128 * 64];
    __shared__ unsigned short Klo[128 * 64];

    const int bh = blockIdx.z;
    const int b = bh / H_, h = bh % H_;
    const int i0 = blockIdx.y * 128;
    const int j0 = blockIdx.x * 128;
    const int tid  = threadIdx.x;
    const int wv   = tid >> 6;
    const int lane = tid & 63;
    const int l15  = lane & 15;
    const int quad = lane >> 4;

    // ---- stage: pure bf16x8 copies from pre-split q/k ----
    #pragma unroll
    for (int it = 0; it < 4; ++it) {
        int idx = it * 256 + tid;
        int r = idx >> 3, c8 = idx & 7;
        int o = r * 64 + (((c8 ^ (r & 7)) << 3));
        size_t gq = ((size_t)b * S_ + i0 + r) * E_ + h * D_ + c8 * 8;
        size_t gk = ((size_t)b * S_ + j0 + r) * E_ + h * D_ + c8 * 8;
        *(bf16x8*)&Qhi[o] = *(const bf16x8*)&qhi_g[gq];
        *(bf16x8*)&Qlo[o] = *(const bf16x8*)&qlo_g[gq];
        *(bf16x8*)&Khi[o] = *(const bf16x8*)&khi_g[gk];
        *(bf16x8*)&Klo[o] = *(const bf16x8*)&klo_g[gk];
    }
    __syncthreads();

    // ---- MFMA compute ----
    f32x4 acc[2][8] = {};
    #pragma unroll
    for (int kk = 0; kk < 64; kk += 32) {
        bf16x8 aHi[2], aLo[2];
        #pragma unroll
        for (int ti = 0; ti < 2; ++ti) {
            int ar = wv * 32 + ti * 16 + l15;
            int sh = kk + quad * 8;
            aHi[ti] = *(const bf16x8*)&Qhi[lds_off(ar, sh)];
            aLo[ti] = *(const bf16x8*)&Qlo[lds_off(ar, sh)];
        }
        #pragma unroll
        for (int tj = 0; tj < 8; ++tj) {
            int br = tj * 16 + l15;
            int sh = kk + quad * 8;
            bf16x8 bHi = *(const bf16x8*)&Khi[lds_off(br, sh)];
            bf16x8 bLo = *(const bf16x8*)&Klo[lds_off(br, sh)];
            #pragma unroll
            for (int ti = 0; ti < 2; ++ti) {
                acc[ti][tj] = __builtin_amdgcn_mfma_f32_16x16x32_bf16(aHi[ti], bHi, acc[ti][tj], 0, 0, 0);
                acc[ti][tj] = __builtin_amdgcn_mfma_f32_16x16x32_bf16(aHi[ti], bLo, acc[ti][tj], 0, 0, 0);
                acc[ti][tj] = __builtin_amdgcn_mfma_f32_16x16x32_bf16(aLo[ti], bHi, acc[ti][tj], 0, 0, 0);
            }
        }
    }

    // ---- epilogue: exp, store, rowsum ----
    const float tbv = tb[bh];
    const int* mrow = mask + b * S_ + j0;
    int m_[8];
    #pragma unroll
    for (int tj = 0; tj < 8; ++tj) m_[tj] = mrow[tj * 16 + l15];

    float* attnbase = attn + (size_t)bh * S_ * S_;
    #pragma unroll
    for (int ti = 0; ti < 2; ++ti) {
        float rs[4] = {0.f, 0.f, 0.f, 0.f};
        const int ib = i0 + wv * 32 + ti * 16 + quad * 4;
        #pragma unroll
        for (int tj = 0; tj < 8; ++tj) {
            f32x4 a = acc[ti][tj];
            #pragma unroll
            for (int r = 0; r < 4; ++r) {
                float sc = a[r] * 0.125f + tbv;
                float p = m_[tj] ? __expf(sc) : 0.f;
                attnbase[(size_t)(ib + r) * S_ + j0 + tj * 16 + l15] = p;
                rs[r] += p;
            }
        }
        #pragma unroll
        for (int off = 1; off < 16; off <<= 1) {
            #pragma unroll
            for (int r = 0; r < 4; ++r)
                rs[r] += __shfl_xor(rs[r], off, 64);
        }
        if (l15 == 0) {
            #pragma unroll
            for (int r = 0; r < 4; ++r)
                atomicAdd(&rowsum[(size_t)bh * S_ + ib + r], rs[r]);
        }
    }
}

// ---------------------------------------------------------------------------
// ctx = softmax(p) @ v via split-bf16 MFMA, fused normalization write-back.
// Block: 64 q-rows x D=64, grid (S/64, B*H) = (32, 24). 4 waves, each owns
// 16 rows x 64 d as 1x4 grid of 16x16 tiles. V^T pre-split [bh][d][S].
// Output written pre-split (Chi/Clo) for the O-gemm.
// ---------------------------------------------------------------------------
__global__ __launch_bounds__(256)
void ctx_mfma(float* __restrict__ attn, const float* __restrict__ rowsum,
              const unsigned short* __restrict__ Vthi_g,
              const unsigned short* __restrict__ Vtlo_g,
              unsigned short* __restrict__ ctxhi, unsigned short* __restrict__ ctxlo) {
    __shared__ unsigned short Phi[64 * 64];
    __shared__ unsigned short Plo[64 * 64];
    __shared__ unsigned short Vhi[64 * 64];
    __shared__ unsigned short Vlo[64 * 64];
    __shared__ float invs[64];

    const int bh = blockIdx.y;
    const int b = bh / H_, h = bh % H_;
    const int i0 = blockIdx.x * 64;
    const int tid  = threadIdx.x;
    const int wv   = tid >> 6;
    const int lane = tid & 63;
    const int l15  = lane & 15;
    const int quad = lane >> 4;

    if (tid < 64)
        invs[tid] = 1.0f / rowsum[(size_t)bh * S_ + i0 + tid];
    __syncthreads();

    f32x4 acc[4] = {};

    for (int kc = 0; kc < S_; kc += 64) {
        // ---- stage P: read attn, normalize, write back, split to LDS ----
        #pragma unroll
        for (int it = 0; it < 4; ++it) {
            int idx = it * 256 + tid;
            int row = idx >> 4, c4 = idx & 15;
            size_t pa = ((size_t)bh * S_ + i0 + row) * S_ + kc + c4 * 4;
            float4 p = *(const float4*)&attn[pa];
            float iv = invs[row];
            p.x *= iv; p.y *= iv; p.z *= iv; p.w *= iv;
            *(float4*)&attn[pa] = p;
            ushort4 ph, pl;
            split1(p.x, ph.x, pl.x); split1(p.y, ph.y, pl.y);
            split1(p.z, ph.z, pl.z); split1(p.w, ph.w, pl.w);
            int o = lds_off(row, c4 * 4);
            *(ushort4*)&Phi[o] = ph;  *(ushort4*)&Plo[o] = pl;
        }
        // ---- stage V^T chunk: pure copies ----
        #pragma unroll
        for (int it = 0; it < 2; ++it) {
            int idx = it * 256 + tid;
            int r = idx >> 3, c8 = idx & 7;
            int o = r * 64 + (((c8 ^ (r & 7)) << 3));
            size_t va = ((size_t)bh * 64 + r) * S_ + kc + c8 * 8;
            *(bf16x8*)&Vhi[o] = *(const bf16x8*)&Vthi_g[va];
            *(bf16x8*)&Vlo[o] = *(const bf16x8*)&Vtlo_g[va];
        }
        __syncthreads();

        #pragma unroll
        for (int kk = 0; kk < 64; kk += 32) {
            int sh = kk + quad * 8;
            bf16x8 aH = *(const bf16x8*)&Phi[lds_off(wv * 16 + l15, sh)];
            bf16x8 aL = *(const bf16x8*)&Plo[lds_off(wv * 16 + l15, sh)];
            #pragma unroll
            for (int tj = 0; tj < 4; ++tj) {
                bf16x8 bH = *(const bf16x8*)&Vhi[lds_off(tj * 16 + l15, sh)];
                bf16x8 bL = *(const bf16x8*)&Vlo[lds_off(tj * 16 + l15, sh)];
                acc[tj] = __builtin_amdgcn_mfma_f32_16x16x32_bf16(aH, bH, acc[tj], 0, 0, 0);
                acc[tj] = __builtin_amdgcn_mfma_f32_16x16x32_bf16(aH, bL, acc[tj], 0, 0, 0);
                acc[tj] = __builtin_amdgcn_mfma_f32_16x16x32_bf16(aL, bH, acc[tj], 0, 0, 0);
            }
        }
        __syncthreads();
    }

    // ---- epilogue: split ctx to bf16 hi/lo for the O-gemm ----
    const int ib = i0 + wv * 16 + quad * 4;
    #pragma unroll
    for (int tj = 0; tj < 4; ++tj) {
        int d = tj * 16 + l15;
        f32x4 a = acc[tj];
        #pragma unroll
        for (int r = 0; r < 4; ++r) {
            unsigned short hh, ll;
            split1(a[r], hh, ll);
            size_t oa = ((size_t)b * S_ + ib + r) * E_ + h * D_ + d;
            ctxhi[oa] = hh;
            ctxlo[oa] = ll;
        }
    }
}

// ---------------------------------------------------------------------------
extern "C" void kernel_launch(void* const* d_in, const int* in_sizes, int n_in,
                              void* d_out, int out_size, void* d_ws, size_t ws_size,
                              hipStream_t stream) {
    const float* query     = (const float*)d_in[0];
    const float* key       = (const float*)d_in[1];
    const float* value     = (const float*)d_in[2];
    const float* task_bias = (const float*)d_in[3];
    const int*   mask      = (const int*)  d_in[4];
    const float* Wq  = (const float*)d_in[5];
    const float* bq  = (const float*)d_in[6];
    const float* Wk  = (const float*)d_in[7];
    const float* bk  = (const float*)d_in[8];
    const float* Wv  = (const float*)d_in[9];
    const float* bv  = (const float*)d_in[10];
    const float* Wtb = (const float*)d_in[11];
    const float* btb = (const float*)d_in[12];
    const float* Wo  = (const float*)d_in[13];
    const float* bo  = (const float*)d_in[14];

    const size_t BSE = (size_t)B_ * S_ * E_;
    const size_t EE  = (size_t)E_ * E_;
    float* out  = (float*)d_out;
    float* attn = (float*)d_out + BSE;

    // --- workspace: 8 x BSE bf16 arrays + rowsum + tb (= previous 50.6 MB) ---
    unsigned short* qhi  = (unsigned short*)d_ws;
    unsigned short* qlo  = qhi  + BSE;
    unsigned short* khi  = qlo  + BSE;
    unsigned short* klo  = khi  + BSE;
    unsigned short* vthi = klo  + BSE;
    unsigned short* vtlo = vthi + BSE;
    unsigned short* chi  = vtlo + BSE;
    unsigned short* clo  = chi  + BSE;
    float* rowsum = (float*)(clo + BSE);
    float* tbws   = rowsum + (size_t)B_ * H_ * S_;

    // --- pre-scores scratch inside the (still dead) attn output region ---
    unsigned short* aqhi = (unsigned short*)attn;
    unsigned short* aqlo = aqhi + BSE;
    unsigned short* akhi = aqlo + BSE;
    unsigned short* aklo = akhi + BSE;
    unsigned short* avhi = aklo + BSE;
    unsigned short* avlo = avhi + BSE;
    unsigned short* wqhi = avlo + BSE;
    unsigned short* wqlo = wqhi + EE;
    unsigned short* wkhi = wqlo + EE;
    unsigned short* wklo = wkhi + EE;
    unsigned short* wvhi = wklo + EE;
    unsigned short* wvlo = wvhi + EE;

    hipMemsetAsync(rowsum, 0, (size_t)B_ * H_ * S_ * sizeof(float), stream);

    const dim3 blk(256);

    // --- one-time splits (BW-bound) ---
    split_kernel<<<dim3(2048), blk, 0, stream>>>(query, aqhi, aqlo, (int)(BSE / 4));
    split_kernel<<<dim3(2048), blk, 0, stream>>>(key,   akhi, aklo, (int)(BSE / 4));
    split_kernel<<<dim3(2048), blk, 0, stream>>>(value, avhi, avlo, (int)(BSE / 4));
    split_kernel<<<dim3(576),  blk, 0, stream>>>(Wq, wqhi, wqlo, (int)(EE / 4));
    split_kernel<<<dim3(576),  blk, 0, stream>>>(Wk, wkhi, wklo, (int)(EE / 4));
    split_kernel<<<dim3(576),  blk, 0, stream>>>(Wv, wvhi, wvlo, (int)(EE / 4));
    tb_kernel<<<1, 64, 0, stream>>>(task_bias, Wtb, btb, tbws);

    const dim3 gProj(E_ / 128, (B_ * S_) / 128);      // (6, 32)
    // Q, K: split bf16 outputs for scores
    gemm_mfma<1, 1><<<gProj, blk, 0, stream>>>(aqhi, aqlo, wqhi, wqlo, nullptr,
                                               bq, nullptr, qhi, qlo,
                                               B_ * S_, E_, E_);
    gemm_mfma<1, 1><<<gProj, blk, 0, stream>>>(akhi, aklo, wkhi, wklo, nullptr,
                                               bk, nullptr, khi, klo,
                                               B_ * S_, E_, E_);
    // V: transposed split output [bh][d][S] for ctx
    gemm_mfma<1, 2><<<gProj, blk, 0, stream>>>(avhi, avlo, wvhi, wvlo, nullptr,
                                               bv, nullptr, vthi, vtlo,
                                               B_ * S_, E_, E_);

    const dim3 gSc(S_ / 128, S_ / 128, B_ * H_);      // (16, 16, 24)
    scores_kernel<<<gSc, blk, 0, stream>>>(qhi, qlo, khi, klo, mask, tbws, attn, rowsum);

    const dim3 gCtx(S_ / 64, B_ * H_);                // (32, 24)
    ctx_mfma<<<gCtx, blk, 0, stream>>>(attn, rowsum, vthi, vtlo, chi, clo);

    // O-gemm: A pre-split (ctx), W fp32 inline-split, fp32 out
    gemm_mfma<0, 0><<<gProj, blk, 0, stream>>>(chi, clo, nullptr, nullptr, Wo,
                                               bo, out, nullptr, nullptr,
                                               B_ * S_, E_, E_);
}

// Round 4
// 812.052 us; speedup vs baseline: 1.3168x; 1.1367x over previous
//
#include <hip/hip_runtime.h>
#include <math.h>

#define B_  2
#define S_  2048
#define E_  768
#define H_  12
#define TB_ 128
#define D_  64

typedef __attribute__((ext_vector_type(4))) float f32x4;
typedef __attribute__((ext_vector_type(8))) short bf16x8;

// ---------------------------------------------------------------------------
// Split-bf16 helpers: x = hi + lo with RNE rounding at each level.
// ---------------------------------------------------------------------------
__device__ inline unsigned short bf16_rne(float x) {
    unsigned u = __float_as_uint(x);
    unsigned r = u + 0x7FFFu + ((u >> 16) & 1u);
    return (unsigned short)(r >> 16);
}
__device__ inline void split1(float x, unsigned short& h, unsigned short& l) {
    h = bf16_rne(x);
    float hf = __uint_as_float((unsigned)h << 16);
    l = bf16_rne(x - hf);
}

// LDS tile [rows][64 bf16], XOR-swizzled in 16B chunks (stride 64, no pad).
__device__ inline int lds_off(int row, int sh) {   // sh = short offset 0..63
    int ch = sh >> 3;                              // 16B chunk 0..7
    int in = sh & 7;
    return row * 64 + (((ch ^ (row & 7)) << 3) | in);
}

// ---------------------------------------------------------------------------
// One-time fp32 -> (hi, lo) bf16 split. Pure BW. n4 = n/4.
// ---------------------------------------------------------------------------
__global__ __launch_bounds__(256)
void split_kernel(const float* __restrict__ in, unsigned short* __restrict__ hi,
                  unsigned short* __restrict__ lo, int n4) {
    int i = blockIdx.x * blockDim.x + threadIdx.x;
    int stride = gridDim.x * blockDim.x;
    for (; i < n4; i += stride) {
        float4 v = *(const float4*)&in[(size_t)i * 4];
        ushort4 h, l;
        split1(v.x, h.x, l.x); split1(v.y, h.y, l.y);
        split1(v.z, h.z, l.z); split1(v.w, h.w, l.w);
        *(ushort4*)&hi[(size_t)i * 4] = h;
        *(ushort4*)&lo[(size_t)i * 4] = l;
    }
}

// ---------------------------------------------------------------------------
// Fused Q/K/V projection GEMM (one dispatch, blockIdx.z selects operand set).
// C[M,N] = A[M,K] @ W[N,K]^T + bias[N], 3-term split-bf16 MFMA.
// z=0 -> Q (split bf16 out), z=1 -> K (split bf16 out), z=2 -> V^T scatter.
// ---------------------------------------------------------------------------
__global__ __launch_bounds__(256)
void qkv_gemm(const unsigned short* __restrict__ aqh, const unsigned short* __restrict__ aql,
              const unsigned short* __restrict__ akh, const unsigned short* __restrict__ akl,
              const unsigned short* __restrict__ avh, const unsigned short* __restrict__ avl,
              const unsigned short* __restrict__ wqh, const unsigned short* __restrict__ wql,
              const unsigned short* __restrict__ wkh, const unsigned short* __restrict__ wkl,
              const unsigned short* __restrict__ wvh, const unsigned short* __restrict__ wvl,
              const float* __restrict__ bq, const float* __restrict__ bk,
              const float* __restrict__ bv,
              unsigned short* __restrict__ qh, unsigned short* __restrict__ ql,
              unsigned short* __restrict__ kh, unsigned short* __restrict__ kl,
              unsigned short* __restrict__ vth, unsigned short* __restrict__ vtl) {
    __shared__ unsigned short Ahs[128 * 64];
    __shared__ unsigned short Als[128 * 64];
    __shared__ unsigned short Whs[128 * 64];
    __shared__ unsigned short Wls[128 * 64];

    const int z = blockIdx.z;
    const unsigned short* Ah_g = z == 0 ? aqh : (z == 1 ? akh : avh);
    const unsigned short* Al_g = z == 0 ? aql : (z == 1 ? akl : avl);
    const unsigned short* Wh_g = z == 0 ? wqh : (z == 1 ? wkh : wvh);
    const unsigned short* Wl_g = z == 0 ? wql : (z == 1 ? wkl : wvl);
    const float* bias = z == 0 ? bq : (z == 1 ? bk : bv);
    unsigned short* Ch = z == 0 ? qh : (z == 1 ? kh : vth);
    unsigned short* Cl = z == 0 ? ql : (z == 1 ? kl : vtl);

    const int m0 = blockIdx.y * 128;
    const int n0 = blockIdx.x * 128;
    const int tid  = threadIdx.x;
    const int wv   = tid >> 6;
    const int lane = tid & 63;
    const int l15  = lane & 15;
    const int quad = lane >> 4;
    const int K = E_, N = E_;

    f32x4 acc[2][8] = {};

    for (int k0 = 0; k0 < K; k0 += 64) {
        #pragma unroll
        for (int it = 0; it < 4; ++it) {
            int idx = it * 256 + tid;
            int r = idx >> 3, c8 = idx & 7;
            int o = r * 64 + (((c8 ^ (r & 7)) << 3));
            size_t ga = (size_t)(m0 + r) * K + k0 + c8 * 8;
            *(bf16x8*)&Ahs[o] = *(const bf16x8*)&Ah_g[ga];
            *(bf16x8*)&Als[o] = *(const bf16x8*)&Al_g[ga];
            size_t gw = (size_t)(n0 + r) * K + k0 + c8 * 8;
            *(bf16x8*)&Whs[o] = *(const bf16x8*)&Wh_g[gw];
            *(bf16x8*)&Wls[o] = *(const bf16x8*)&Wl_g[gw];
        }
        __syncthreads();

        #pragma unroll
        for (int kk = 0; kk < 64; kk += 32) {
            bf16x8 aHi[2], aLo[2];
            #pragma unroll
            for (int ti = 0; ti < 2; ++ti) {
                int ar = wv * 32 + ti * 16 + l15;
                int sh = kk + quad * 8;
                aHi[ti] = *(const bf16x8*)&Ahs[lds_off(ar, sh)];
                aLo[ti] = *(const bf16x8*)&Als[lds_off(ar, sh)];
            }
            #pragma unroll
            for (int tj = 0; tj < 8; ++tj) {
                int br = tj * 16 + l15;
                int sh = kk + quad * 8;
                bf16x8 bHi = *(const bf16x8*)&Whs[lds_off(br, sh)];
                bf16x8 bLo = *(const bf16x8*)&Wls[lds_off(br, sh)];
                #pragma unroll
                for (int ti = 0; ti < 2; ++ti) {
                    acc[ti][tj] = __builtin_amdgcn_mfma_f32_16x16x32_bf16(aHi[ti], bHi, acc[ti][tj], 0, 0, 0);
                    acc[ti][tj] = __builtin_amdgcn_mfma_f32_16x16x32_bf16(aHi[ti], bLo, acc[ti][tj], 0, 0, 0);
                    acc[ti][tj] = __builtin_amdgcn_mfma_f32_16x16x32_bf16(aLo[ti], bHi, acc[ti][tj], 0, 0, 0);
                }
            }
        }
        __syncthreads();
    }

    #pragma unroll
    for (int ti = 0; ti < 2; ++ti) {
        const int ib = m0 + wv * 32 + ti * 16 + quad * 4;
        #pragma unroll
        for (int tj = 0; tj < 8; ++tj) {
            int col = n0 + tj * 16 + l15;
            float bvv = bias[col];
            f32x4 a = acc[ti][tj];
            #pragma unroll
            for (int r = 0; r < 4; ++r) {
                float val = a[r] + bvv;
                unsigned short hh, ll;
                split1(val, hh, ll);
                if (z < 2) {
                    size_t oa = (size_t)(ib + r) * N + col;
                    Ch[oa] = hh; Cl[oa] = ll;
                } else {
                    // V^T scatter: token = ib+r, col = h*64+d -> [bt*H+h][d][s]
                    int token = ib + r;
                    int bt = token >> 11, s = token & (S_ - 1);
                    int hh_ = col >> 6, d = col & 63;
                    size_t oa = ((size_t)(bt * H_ + hh_) * 64 + d) * S_ + s;
                    Ch[oa] = hh; Cl[oa] = ll;
                }
            }
        }
    }
}

// ---------------------------------------------------------------------------
__global__ void tb_kernel(const float* __restrict__ task_bias,
                          const float* __restrict__ Wtb,
                          const float* __restrict__ btb,
                          float* __restrict__ tb) {
    int t = threadIdx.x;
    if (t < B_ * H_) {
        int b = t / H_, h = t % H_;
        float s = 0.f;
        for (int i = 0; i < TB_; ++i)
            s += task_bias[b * TB_ + i] * Wtb[h * TB_ + i];
        tb[t] = s + btb[h];
    }
}

// ---------------------------------------------------------------------------
// Pass A: fused scores+rowsum+PV. Per block: 128 q-rows x full j sweep.
// Grid (S/128, B*H) = (16, 24). 4 waves; wave owns 32 q-rows.
// P never touches HBM: split-bf16 into wave-private LDS rows, PV MFMA.
// Outputs: split ctx (normalized) + inv rowsum. No atomics, no memset.
// ---------------------------------------------------------------------------
__global__ __launch_bounds__(256, 2)
void attn_fused(const unsigned short* __restrict__ qh_g, const unsigned short* __restrict__ ql_g,
                const unsigned short* __restrict__ kh_g, const unsigned short* __restrict__ kl_g,
                const unsigned short* __restrict__ vth_g, const unsigned short* __restrict__ vtl_g,
                const int* __restrict__ mask, const float* __restrict__ tb,
                unsigned short* __restrict__ ch_g, unsigned short* __restrict__ cl_g,
                float* __restrict__ rowsuminv) {
    __shared__ unsigned short Kh[64 * 64];
    __shared__ unsigned short Kl[64 * 64];
    __shared__ unsigned short Vh[64 * 64];
    __shared__ unsigned short Vl[64 * 64];
    __shared__ unsigned short Ph[128 * 64];
    __shared__ unsigned short Pl[128 * 64];

    const int bh = blockIdx.y;
    const int b = bh / H_, h = bh % H_;
    const int i0 = blockIdx.x * 128;
    const int tid  = threadIdx.x;
    const int wv   = tid >> 6;
    const int lane = tid & 63;
    const int l15  = lane & 15;
    const int quad = lane >> 4;

    // ---- Q fragments in registers (loaded once; L2/L3-resident) ----
    bf16x8 qH[2][2], qL[2][2];
    #pragma unroll
    for (int ti = 0; ti < 2; ++ti) {
        int ar = i0 + wv * 32 + ti * 16 + l15;
        #pragma unroll
        for (int kh2 = 0; kh2 < 2; ++kh2) {
            size_t ga = ((size_t)b * S_ + ar) * E_ + h * D_ + kh2 * 32 + quad * 8;
            qH[ti][kh2] = *(const bf16x8*)&qh_g[ga];
            qL[ti][kh2] = *(const bf16x8*)&ql_g[ga];
        }
    }

    const float tbv = tb[bh];
    float rs[2][4] = {};
    f32x4 cacc[2][4] = {};

    #pragma unroll 1
    for (int jt = 0; jt < S_; jt += 64) {
        // ---- stage K (64 j x 64 d) and V^T (64 d x 64 j): pure copies ----
        #pragma unroll
        for (int it = 0; it < 2; ++it) {
            int idx = it * 256 + tid;
            int r = idx >> 3, c8 = idx & 7;
            int o = r * 64 + (((c8 ^ (r & 7)) << 3));
            size_t gk = ((size_t)b * S_ + jt + r) * E_ + h * D_ + c8 * 8;
            *(bf16x8*)&Kh[o] = *(const bf16x8*)&kh_g[gk];
            *(bf16x8*)&Kl[o] = *(const bf16x8*)&kl_g[gk];
            size_t gv = ((size_t)bh * 64 + r) * S_ + jt + c8 * 8;
            *(bf16x8*)&Vh[o] = *(const bf16x8*)&vth_g[gv];
            *(bf16x8*)&Vl[o] = *(const bf16x8*)&vtl_g[gv];
        }
        __syncthreads();

        // ---- QK MFMA: s tile 32 rows x 64 j per wave ----
        f32x4 sacc[2][4] = {};
        #pragma unroll
        for (int kk2 = 0; kk2 < 2; ++kk2) {
            int sh = kk2 * 32 + quad * 8;
            #pragma unroll
            for (int tj = 0; tj < 4; ++tj) {
                bf16x8 bHi = *(const bf16x8*)&Kh[lds_off(tj * 16 + l15, sh)];
                bf16x8 bLo = *(const bf16x8*)&Kl[lds_off(tj * 16 + l15, sh)];
                #pragma unroll
                for (int ti = 0; ti < 2; ++ti) {
                    sacc[ti][tj] = __builtin_amdgcn_mfma_f32_16x16x32_bf16(qH[ti][kk2], bHi, sacc[ti][tj], 0, 0, 0);
                    sacc[ti][tj] = __builtin_amdgcn_mfma_f32_16x16x32_bf16(qH[ti][kk2], bLo, sacc[ti][tj], 0, 0, 0);
                    sacc[ti][tj] = __builtin_amdgcn_mfma_f32_16x16x32_bf16(qL[ti][kk2], bHi, sacc[ti][tj], 0, 0, 0);
                }
            }
        }

        // ---- exp + rowsum + split-P to (wave-private) LDS ----
        int m_[4];
        #pragma unroll
        for (int tj = 0; tj < 4; ++tj) m_[tj] = mask[b * S_ + jt + tj * 16 + l15];

        #pragma unroll
        for (int ti = 0; ti < 2; ++ti) {
            #pragma unroll
            for (int tj = 0; tj < 4; ++tj) {
                f32x4 a = sacc[ti][tj];
                #pragma unroll
                for (int r = 0; r < 4; ++r) {
                    float p = m_[tj] ? __expf(a[r] * 0.125f + tbv) : 0.f;
                    rs[ti][r] += p;
                    int prow = wv * 32 + ti * 16 + quad * 4 + r;
                    int pcol = tj * 16 + l15;
                    unsigned short hh, ll;
                    split1(p, hh, ll);
                    int off = prow * 64 + ((((pcol >> 3) ^ (prow & 7)) << 3) | (pcol & 7));
                    Ph[off] = hh; Pl[off] = ll;
                }
            }
        }

        // ---- PV MFMA (wave reads only its own P rows; no barrier needed) ----
        #pragma unroll
        for (int kk2 = 0; kk2 < 2; ++kk2) {
            int sh = kk2 * 32 + quad * 8;
            bf16x8 aHi[2], aLo[2];
            #pragma unroll
            for (int ti = 0; ti < 2; ++ti) {
                int ar = wv * 32 + ti * 16 + l15;
                aHi[ti] = *(const bf16x8*)&Ph[lds_off(ar, sh)];
                aLo[ti] = *(const bf16x8*)&Pl[lds_off(ar, sh)];
            }
            #pragma unroll
            for (int td = 0; td < 4; ++td) {
                bf16x8 bHi = *(const bf16x8*)&Vh[lds_off(td * 16 + l15, sh)];
                bf16x8 bLo = *(const bf16x8*)&Vl[lds_off(td * 16 + l15, sh)];
                #pragma unroll
                for (int ti = 0; ti < 2; ++ti) {
                    cacc[ti][td] = __builtin_amdgcn_mfma_f32_16x16x32_bf16(aHi[ti], bHi, cacc[ti][td], 0, 0, 0);
                    cacc[ti][td] = __builtin_amdgcn_mfma_f32_16x16x32_bf16(aHi[ti], bLo, cacc[ti][td], 0, 0, 0);
                    cacc[ti][td] = __builtin_amdgcn_mfma_f32_16x16x32_bf16(aLo[ti], bHi, cacc[ti][td], 0, 0, 0);
                }
            }
        }
        __syncthreads();   // protect K/V (and P reuse) before next stage
    }

    // ---- finalize: reduce rowsum over the 16-lane groups ----
    #pragma unroll
    for (int ti = 0; ti < 2; ++ti)
        #pragma unroll
        for (int r = 0; r < 4; ++r)
            #pragma unroll
            for (int off = 1; off < 16; off <<= 1)
                rs[ti][r] += __shfl_xor(rs[ti][r], off, 64);

    // lanes' rs[ti][r] now hold exactly the rowsums of the rows their cacc holds
    #pragma unroll
    for (int ti = 0; ti < 2; ++ti) {
        float inv_[4];
        #pragma unroll
        for (int r = 0; r < 4; ++r) {
            inv_[r] = 1.0f / rs[ti][r];
            if (l15 == 0) {
                int row = i0 + wv * 32 + ti * 16 + quad * 4 + r;
                rowsuminv[(size_t)bh * S_ + row] = inv_[r];
            }
        }
        #pragma unroll
        for (int td = 0; td < 4; ++td) {
            #pragma unroll
            for (int r = 0; r < 4; ++r) {
                float val = cacc[ti][td][r] * inv_[r];
                unsigned short hh, ll;
                split1(val, hh, ll);
                int row = i0 + wv * 32 + ti * 16 + quad * 4 + r;
                size_t oa = ((size_t)b * S_ + row) * E_ + h * D_ + td * 16 + l15;
                ch_g[oa] = hh; cl_g[oa] = ll;
            }
        }
    }
}

// ---------------------------------------------------------------------------
// Pass B: recompute scores, scale by final inv rowsum, write normalized attn.
// Identical MFMA sequence to pass A -> bitwise-consistent with its rowsum.
// ---------------------------------------------------------------------------
__global__ __launch_bounds__(256)
void attn_write(const unsigned short* __restrict__ qhi_g,
                const unsigned short* __restrict__ qlo_g,
                const unsigned short* __restrict__ khi_g,
                const unsigned short* __restrict__ klo_g,
                const int* __restrict__ mask, const float* __restrict__ tb,
                const float* __restrict__ rowsuminv,
                float* __restrict__ attn) {
    __shared__ unsigned short Qhi[128 * 64];
    __shared__ unsigned short Qlo[128 * 64];
    __shared__ unsigned short Khi[128 * 64];
    __shared__ unsigned short Klo[128 * 64];

    const int bh = blockIdx.z;
    const int b = bh / H_, h = bh % H_;
    const int i0 = blockIdx.y * 128;
    const int j0 = blockIdx.x * 128;
    const int tid  = threadIdx.x;
    const int wv   = tid >> 6;
    const int lane = tid & 63;
    const int l15  = lane & 15;
    const int quad = lane >> 4;

    #pragma unroll
    for (int it = 0; it < 4; ++it) {
        int idx = it * 256 + tid;
        int r = idx >> 3, c8 = idx & 7;
        int o = r * 64 + (((c8 ^ (r & 7)) << 3));
        size_t gq = ((size_t)b * S_ + i0 + r) * E_ + h * D_ + c8 * 8;
        size_t gk = ((size_t)b * S_ + j0 + r) * E_ + h * D_ + c8 * 8;
        *(bf16x8*)&Qhi[o] = *(const bf16x8*)&qhi_g[gq];
        *(bf16x8*)&Qlo[o] = *(const bf16x8*)&qlo_g[gq];
        *(bf16x8*)&Khi[o] = *(const bf16x8*)&khi_g[gk];
        *(bf16x8*)&Klo[o] = *(const bf16x8*)&klo_g[gk];
    }
    __syncthreads();

    f32x4 acc[2][8] = {};
    #pragma unroll
    for (int kk = 0; kk < 64; kk += 32) {
        bf16x8 aHi[2], aLo[2];
        #pragma unroll
        for (int ti = 0; ti < 2; ++ti) {
            int ar = wv * 32 + ti * 16 + l15;
            int sh = kk + quad * 8;
            aHi[ti] = *(const bf16x8*)&Qhi[lds_off(ar, sh)];
            aLo[ti] = *(const bf16x8*)&Qlo[lds_off(ar, sh)];
        }
        #pragma unroll
        for (int tj = 0; tj < 8; ++tj) {
            int br = tj * 16 + l15;
            int sh = kk + quad * 8;
            bf16x8 bHi = *(const bf16x8*)&Khi[lds_off(br, sh)];
            bf16x8 bLo = *(const bf16x8*)&Klo[lds_off(br, sh)];
            #pragma unroll
            for (int ti = 0; ti < 2; ++ti) {
                acc[ti][tj] = __builtin_amdgcn_mfma_f32_16x16x32_bf16(aHi[ti], bHi, acc[ti][tj], 0, 0, 0);
                acc[ti][tj] = __builtin_amdgcn_mfma_f32_16x16x32_bf16(aHi[ti], bLo, acc[ti][tj], 0, 0, 0);
                acc[ti][tj] = __builtin_amdgcn_mfma_f32_16x16x32_bf16(aLo[ti], bHi, acc[ti][tj], 0, 0, 0);
            }
        }
    }

    const float tbv = tb[bh];
    const int* mrow = mask + b * S_ + j0;
    int m_[8];
    #pragma unroll
    for (int tj = 0; tj < 8; ++tj) m_[tj] = mrow[tj * 16 + l15];

    float* attnbase = attn + (size_t)bh * S_ * S_;
    #pragma unroll
    for (int ti = 0; ti < 2; ++ti) {
        const int ib = i0 + wv * 32 + ti * 16 + quad * 4;
        float inv_[4];
        #pragma unroll
        for (int r = 0; r < 4; ++r)
            inv_[r] = rowsuminv[(size_t)bh * S_ + ib + r];
        #pragma unroll
        for (int tj = 0; tj < 8; ++tj) {
            f32x4 a = acc[ti][tj];
            #pragma unroll
            for (int r = 0; r < 4; ++r) {
                float sc = a[r] * 0.125f + tbv;
                float p = m_[tj] ? __expf(sc) * inv_[r] : 0.f;
                attnbase[(size_t)(ib + r) * S_ + j0 + tj * 16 + l15] = p;
            }
        }
    }
}

// ---------------------------------------------------------------------------
// Output GEMM (pre-split A and W): C = A @ W^T + bias, fp32 out.
// ---------------------------------------------------------------------------
__global__ __launch_bounds__(256)
void out_gemm(const unsigned short* __restrict__ Ahi_g,
              const unsigned short* __restrict__ Alo_g,
              const unsigned short* __restrict__ Whi_g,
              const unsigned short* __restrict__ Wlo_g,
              const float* __restrict__ bias, float* __restrict__ Cf) {
    __shared__ unsigned short Ahs[128 * 64];
    __shared__ unsigned short Als[128 * 64];
    __shared__ unsigned short Whs[128 * 64];
    __shared__ unsigned short Wls[128 * 64];

    const int m0 = blockIdx.y * 128;
    const int n0 = blockIdx.x * 128;
    const int tid  = threadIdx.x;
    const int wv   = tid >> 6;
    const int lane = tid & 63;
    const int l15  = lane & 15;
    const int quad = lane >> 4;
    const int K = E_, N = E_;

    f32x4 acc[2][8] = {};

    for (int k0 = 0; k0 < K; k0 += 64) {
        #pragma unroll
        for (int it = 0; it < 4; ++it) {
            int idx = it * 256 + tid;
            int r = idx >> 3, c8 = idx & 7;
            int o = r * 64 + (((c8 ^ (r & 7)) << 3));
            size_t ga = (size_t)(m0 + r) * K + k0 + c8 * 8;
            *(bf16x8*)&Ahs[o] = *(const bf16x8*)&Ahi_g[ga];
            *(bf16x8*)&Als[o] = *(const bf16x8*)&Alo_g[ga];
            size_t gw = (size_t)(n0 + r) * K + k0 + c8 * 8;
            *(bf16x8*)&Whs[o] = *(const bf16x8*)&Whi_g[gw];
            *(bf16x8*)&Wls[o] = *(const bf16x8*)&Wlo_g[gw];
        }
        __syncthreads();

        #pragma unroll
        for (int kk = 0; kk < 64; kk += 32) {
            bf16x8 aHi[2], aLo[2];
            #pragma unroll
            for (int ti = 0; ti < 2; ++ti) {
                int ar = wv * 32 + ti * 16 + l15;
                int sh = kk + quad * 8;
                aHi[ti] = *(const bf16x8*)&Ahs[lds_off(ar, sh)];
                aLo[ti] = *(const bf16x8*)&Als[lds_off(ar, sh)];
            }
            #pragma unroll
            for (int tj = 0; tj < 8; ++tj) {
                int br = tj * 16 + l15;
                int sh = kk + quad * 8;
                bf16x8 bHi = *(const bf16x8*)&Whs[lds_off(br, sh)];
                bf16x8 bLo = *(const bf16x8*)&Wls[lds_off(br, sh)];
                #pragma unroll
                for (int ti = 0; ti < 2; ++ti) {
                    acc[ti][tj] = __builtin_amdgcn_mfma_f32_16x16x32_bf16(aHi[ti], bHi, acc[ti][tj], 0, 0, 0);
                    acc[ti][tj] = __builtin_amdgcn_mfma_f32_16x16x32_bf16(aHi[ti], bLo, acc[ti][tj], 0, 0, 0);
                    acc[ti][tj] = __builtin_amdgcn_mfma_f32_16x16x32_bf16(aLo[ti], bHi, acc[ti][tj], 0, 0, 0);
                }
            }
        }
        __syncthreads();
    }

    #pragma unroll
    for (int ti = 0; ti < 2; ++ti) {
        const int ib = m0 + wv * 32 + ti * 16 + quad * 4;
        #pragma unroll
        for (int tj = 0; tj < 8; ++tj) {
            int col = n0 + tj * 16 + l15;
            float bvv = bias[col];
            f32x4 a = acc[ti][tj];
            #pragma unroll
            for (int r = 0; r < 4; ++r)
                Cf[(size_t)(ib + r) * N + col] = a[r] + bvv;
        }
    }
}

// ---------------------------------------------------------------------------
extern "C" void kernel_launch(void* const* d_in, const int* in_sizes, int n_in,
                              void* d_out, int out_size, void* d_ws, size_t ws_size,
                              hipStream_t stream) {
    const float* query     = (const float*)d_in[0];
    const float* key       = (const float*)d_in[1];
    const float* value     = (const float*)d_in[2];
    const float* task_bias = (const float*)d_in[3];
    const int*   mask      = (const int*)  d_in[4];
    const float* Wq  = (const float*)d_in[5];
    const float* bq  = (const float*)d_in[6];
    const float* Wk  = (const float*)d_in[7];
    const float* bk  = (const float*)d_in[8];
    const float* Wv  = (const float*)d_in[9];
    const float* bv  = (const float*)d_in[10];
    const float* Wtb = (const float*)d_in[11];
    const float* btb = (const float*)d_in[12];
    const float* Wo  = (const float*)d_in[13];
    const float* bo  = (const float*)d_in[14];

    const size_t BSE = (size_t)B_ * S_ * E_;
    const size_t EE  = (size_t)E_ * E_;
    float* out  = (float*)d_out;
    float* attn = (float*)d_out + BSE;

    // --- workspace: 8 x BSE bf16 + rowsuminv + tb (same footprint as before) ---
    unsigned short* qhi  = (unsigned short*)d_ws;
    unsigned short* qlo  = qhi  + BSE;
    unsigned short* khi  = qlo  + BSE;
    unsigned short* klo  = khi  + BSE;
    unsigned short* vthi = klo  + BSE;
    unsigned short* vtlo = vthi + BSE;
    unsigned short* chi  = vtlo + BSE;
    unsigned short* clo  = chi  + BSE;
    float* rsinv  = (float*)(clo + BSE);
    float* tbws   = rsinv + (size_t)B_ * H_ * S_;

    // --- pre-QKV scratch inside the (dead until attn_write) attn region ---
    unsigned short* aqhi = (unsigned short*)attn;
    unsigned short* aqlo = aqhi + BSE;
    unsigned short* akhi = aqlo + BSE;
    unsigned short* aklo = akhi + BSE;
    unsigned short* avhi = aklo + BSE;
    unsigned short* avlo = avhi + BSE;
    unsigned short* wqhi = avlo + BSE;
    unsigned short* wqlo = wqhi + EE;
    unsigned short* wkhi = wqlo + EE;
    unsigned short* wklo = wkhi + EE;
    unsigned short* wvhi = wklo + EE;
    unsigned short* wvlo = wvhi + EE;

    // --- Wo splits go into the vthi region (dead after attn_fused) ---
    unsigned short* wohi = vthi;
    unsigned short* wolo = vthi + EE;

    const dim3 blk(256);

    // one-time splits (BW-bound)
    split_kernel<<<dim3(2048), blk, 0, stream>>>(query, aqhi, aqlo, (int)(BSE / 4));
    split_kernel<<<dim3(2048), blk, 0, stream>>>(key,   akhi, aklo, (int)(BSE / 4));
    split_kernel<<<dim3(2048), blk, 0, stream>>>(value, avhi, avlo, (int)(BSE / 4));
    split_kernel<<<dim3(576),  blk, 0, stream>>>(Wq, wqhi, wqlo, (int)(EE / 4));
    split_kernel<<<dim3(576),  blk, 0, stream>>>(Wk, wkhi, wklo, (int)(EE / 4));
    split_kernel<<<dim3(576),  blk, 0, stream>>>(Wv, wvhi, wvlo, (int)(EE / 4));
    tb_kernel<<<1, 64, 0, stream>>>(task_bias, Wtb, btb, tbws);

    // fused Q/K/V projections: one dispatch, 576 blocks
    const dim3 gQKV(E_ / 128, (B_ * S_) / 128, 3);    // (6, 32, 3)
    qkv_gemm<<<gQKV, blk, 0, stream>>>(aqhi, aqlo, akhi, aklo, avhi, avlo,
                                       wqhi, wqlo, wkhi, wklo, wvhi, wvlo,
                                       bq, bk, bv,
                                       qhi, qlo, khi, klo, vthi, vtlo);

    // pass A: fused scores+rowsum+PV (P stays on-chip)
    const dim3 gA(S_ / 128, B_ * H_);                 // (16, 24)
    attn_fused<<<gA, blk, 0, stream>>>(qhi, qlo, khi, klo, vthi, vtlo,
                                       mask, tbws, chi, clo, rsinv);

    // Wo split (into vthi region, now dead)
    split_kernel<<<dim3(576), blk, 0, stream>>>(Wo, wohi, wolo, (int)(EE / 4));

    // pass B: recompute scores, write normalized attn once
    const dim3 gB(S_ / 128, S_ / 128, B_ * H_);       // (16, 16, 24)
    attn_write<<<gB, blk, 0, stream>>>(qhi, qlo, khi, klo, mask, tbws, rsinv, attn);

    // output projection
    const dim3 gO(E_ / 128, (B_ * S_) / 128);         // (6, 32)
    out_gemm<<<gO, blk, 0, stream>>>(chi, clo, wohi, wolo, bo, out);
}